// Round 7
// baseline (997.747 us; speedup 1.0000x reference)
//
#include <hip/hip_runtime.h>

#define N_NODES 100000
#define N_EDGES 3200000
#define IN_DIM  512
#define HD_DIM  256
#define OUT_DIM 128

#define NBINS  1563        // 64-row bins: bin = row >> 6
#define BINCAP 2560        // slots per bin: mean 2048, sigma ~45 -> 11+ sigma
#define SORT_IT 10         // BINCAP / 256
#define NSEG   13          // col segment = col >> 13 (8192 rows = 4 MB of H per seg)
#define NKEYS  (NSEG * 64) // 832 sort keys: seg*64 + row_local
#define EPT    16          // edges per thread in scatter pass
#define EPB    (256 * EPT) // edges per block = 4096

typedef short   short8  __attribute__((ext_vector_type(8)));
typedef unsigned short ushort8 __attribute__((ext_vector_type(8)));
typedef float   floatx4 __attribute__((ext_vector_type(4)));

__device__ __forceinline__ unsigned short f2bf(float f) {
    unsigned int u = __float_as_uint(f);
    u += 0x7fffu + ((u >> 16) & 1u);   // round-to-nearest-even
    return (unsigned short)(u >> 16);
}

// HW packed fp32->bf16 (RNE), 2 elements per instruction
__device__ __forceinline__ unsigned f2bf_pk(float lo, float hi) {
    unsigned r;
    asm("v_cvt_pk_bf16_f32 %0, %1, %2" : "=v"(r) : "v"(lo), "v"(hi));
    return r;
}

// ---------------- CSR build level 1: scatter edges into 64-row bins ----------------
// binned layout: bin b owns slots [b*BINCAP, b*BINCAP + cnt[b]); gaps never read.
// packed entry: x = (row_local6 << 26) | col(17b), y = bits(val)

__global__ __launch_bounds__(256) void bin_scatter(const int* __restrict__ erow,
                                                   const int* __restrict__ ecol,
                                                   const float* __restrict__ eval,
                                                   int* __restrict__ gcnt,
                                                   uint2* __restrict__ binned, int E) {
    __shared__ int hist[NBINS];
    __shared__ int cur[NBINS];
    __shared__ int gbase[NBINS];
    const int t = threadIdx.x;
    for (int i = t; i < NBINS; i += 256) hist[i] = 0;
    __syncthreads();

    long base = (long)blockIdx.x * EPB + t * EPT;
    int rows[EPT];
    const bool valid = base < E;   // chunks all-in or all-out (E % 16 == 0)
    if (valid) {
        const int4* p = (const int4*)(erow + base);
#pragma unroll
        for (int v = 0; v < 4; v++) {
            int4 r = p[v];
            rows[4 * v + 0] = r.x; rows[4 * v + 1] = r.y;
            rows[4 * v + 2] = r.z; rows[4 * v + 3] = r.w;
        }
#pragma unroll
        for (int u = 0; u < EPT; u++) atomicAdd(&hist[rows[u] >> 6], 1);
    }
    __syncthreads();

    // reserve a contiguous run in each touched bin
    for (int i = t; i < NBINS; i += 256) {
        int h = hist[i];
        cur[i] = 0;
        gbase[i] = h ? (i * BINCAP + atomicAdd(&gcnt[i], h)) : 0;
    }
    __syncthreads();

    if (valid) {
        const int4*   pc = (const int4*)(ecol + base);
        const float4* pv = (const float4*)(eval + base);
#pragma unroll
        for (int v = 0; v < 4; v++) {
            int4 c4 = pc[v];
            float4 v4 = pv[v];
            int   cs[4] = {c4.x, c4.y, c4.z, c4.w};
            float vs[4] = {v4.x, v4.y, v4.z, v4.w};
#pragma unroll
            for (int u = 0; u < 4; u++) {
                int r = rows[4 * v + u];
                int bin = r >> 6;
                int lofs = atomicAdd(&cur[bin], 1);
                binned[gbase[bin] + lofs] =
                    make_uint2(((unsigned)(r & 63) << 26) | (unsigned)cs[u],
                               __float_as_uint(vs[u]));
            }
        }
    }
}

// ---------------- fused sort + segment-major SPMM (used for BOTH passes) ----------------
// One block per 64-row bin. Sort the bin's edges by key = (col>>13)*64 + row_local in LDS,
// then gather in column-SEGMENT order: all co-resident blocks sweep the same 4MB H slice
// simultaneously -> gathers become L2-resident. No CSR materialization needed.

__global__ __launch_bounds__(256) void spmm_seg(const int* __restrict__ gcnt,
                                                const uint2* __restrict__ binned,
                                                const unsigned short* __restrict__ Hin,
                                                unsigned short* __restrict__ Hout) {
    __shared__ uint2 ssort[BINCAP];   // 20 KB
    __shared__ int sd[1024];          // key histogram -> inclusive scan (padded)
    __shared__ int cur[NKEYS];        // scatter cursors
    const int t = threadIdx.x;
    const int b = blockIdx.x;
    int n = gcnt[b];
    if (n > BINCAP) n = BINCAP;
    const long s = (long)b * BINCAP;

    sd[t] = 0; sd[t + 256] = 0; sd[t + 512] = 0; sd[t + 768] = 0;
    __syncthreads();

    // load bin edges into registers (static indices) + key histogram
    uint2 ereg[SORT_IT];
#pragma unroll
    for (int it = 0; it < SORT_IT; it++) {
        int i = it * 256 + t;
        if (i < n) {
            unsigned long long raw =
                __builtin_nontemporal_load((const unsigned long long*)binned + (s + i));
            ereg[it].x = (unsigned)raw;
            ereg[it].y = (unsigned)(raw >> 32);
            unsigned key = ((ereg[it].x & 0x03FFFFFFu) >> 13) * 64u + (ereg[it].x >> 26);
            atomicAdd(&sd[key], 1);
        }
    }
    __syncthreads();

    // in-place inclusive scan over sd[0..1024)
    for (int off = 1; off < 1024; off <<= 1) {
        int a0 = (t >= off) ? sd[t - off] : 0;
        int a1 = (t + 256 >= off) ? sd[t + 256 - off] : 0;
        int a2 = (t + 512 >= off) ? sd[t + 512 - off] : 0;
        int a3 = (t + 768 >= off) ? sd[t + 768 - off] : 0;
        __syncthreads();
        sd[t] += a0; sd[t + 256] += a1; sd[t + 512] += a2; sd[t + 768] += a3;
        __syncthreads();
    }

    for (int k = t; k < NKEYS; k += 256) cur[k] = (k == 0) ? 0 : sd[k - 1];
    __syncthreads();

    // scatter into key-sorted LDS array
#pragma unroll
    for (int it = 0; it < SORT_IT; it++) {
        int i = it * 256 + t;
        if (i < n) {
            unsigned key = ((ereg[it].x & 0x03FFFFFFu) >> 13) * 64u + (ereg[it].x >> 26);
            int p = atomicAdd(&cur[key], 1);
            ssort[p] = ereg[it];
        }
    }
    __syncthreads();

    // segment-major gather: wave w owns rows [w*16, w*16+16)
    const int wave = t >> 6;
    const int lane = t & 63;
    const uint2* __restrict__ Hv = (const uint2*)Hin;   // H row = 64 uint2
    floatx4 acc[16] = {};

    for (int sg = 0; sg < NSEG; sg++) {
#pragma unroll
        for (int i = 0; i < 16; i++) {
            const int key = sg * 64 + wave * 16 + i;
            int ks = (key == 0) ? 0 : sd[key - 1];
            int ke = sd[key];
            for (int j0 = ks; j0 < ke; j0 += 4) {
                int m = ke - j0;
                if (m > 4) m = 4;
                uint2 h[4];
                float v[4];
#pragma unroll
                for (int u = 0; u < 4; u++) {
                    if (u < m) {                        // wave-uniform predicate
                        uint2 e = ssort[j0 + u];        // broadcast LDS read
                        v[u] = __uint_as_float(e.y);
                        h[u] = Hv[((e.x & 0x03FFFFFFu) << 6) + lane];
                    } else { v[u] = 0.f; h[u] = make_uint2(0u, 0u); }
                }
#pragma unroll
                for (int u = 0; u < 4; u++) {
                    float vu = v[u];
                    acc[i][0] += vu * __uint_as_float(h[u].x << 16);
                    acc[i][1] += vu * __uint_as_float(h[u].x & 0xffff0000u);
                    acc[i][2] += vu * __uint_as_float(h[u].y << 16);
                    acc[i][3] += vu * __uint_as_float(h[u].y & 0xffff0000u);
                }
            }
        }
    }

#pragma unroll
    for (int i = 0; i < 16; i++) {
        const int row = (b << 6) + wave * 16 + i;
        if (row < N_NODES) {
            unsigned long long o =
                (unsigned long long)((unsigned)f2bf(acc[i][0]) | ((unsigned)f2bf(acc[i][1]) << 16))
              | ((unsigned long long)((unsigned)f2bf(acc[i][2]) | ((unsigned)f2bf(acc[i][3]) << 16)) << 32);
            __builtin_nontemporal_store(o, (unsigned long long*)Hout + (((unsigned)row << 6) + lane));
        }
    }
}

// ---------------- fused weight transpose + fp32->bf16: in[K][N] -> out[N][K] ----------------

__global__ void transpose_w(const float* __restrict__ W0, unsigned short* __restrict__ W0T,
                            const float* __restrict__ W1, unsigned short* __restrict__ W1T) {
    int idx = blockIdx.x * blockDim.x + threadIdx.x;
    if (idx < IN_DIM * HD_DIM) {
        int k = idx / HD_DIM, n = idx - k * HD_DIM;
        W0T[n * IN_DIM + k] = f2bf(W0[idx]);
    } else {
        int j = idx - IN_DIM * HD_DIM;
        if (j < HD_DIM * OUT_DIM) {
            int k = j / OUT_DIM, n = j - k * OUT_DIM;
            W1T[n * HD_DIM + k] = f2bf(W1[j]);
        }
    }
}

// ---------------- MFMA bf16 GEMM: C[M,N] = (relu?)A[M,K] @ BT[N,K]^T + bias ----------------
// BK = 32 (R3-proven structure). BN = 128: 4 waves 64x64 (acc[4][4]).
// BN = 256: 4 waves 64x128 (acc[4][8]) -- single block-column so fp32 A is fetched ONCE.

template <bool A_FP32, bool RELU_A, bool OUT_BF16, int BN>
__global__ __launch_bounds__(256, 2) void gemm_mfma(const void* __restrict__ Av,
                                                    const unsigned short* __restrict__ BT,
                                                    const float* __restrict__ bias,
                                                    void* __restrict__ Cv,
                                                    int M, int N, int K) {
    constexpr int NJ = BN / 32;   // N-fragments per wave: 4 or 8
    __shared__ unsigned short As[128 * 40];
    __shared__ unsigned short Bs[BN * 40];
    const int tid  = threadIdx.x;
    const int lane = tid & 63;
    const int wv   = tid >> 6;
    const int wm   = (wv >> 1) * 64;
    const int wn   = (wv & 1) * (BN / 2);
    const int mrow = lane & 15;
    const int q    = lane >> 4;
    const int bm   = blockIdx.x * 128;
    const int bn   = blockIdx.y * BN;

    floatx4 acc[4][NJ] = {};

    const int srow = tid >> 1;
    const int skh  = (tid & 1) * 16;

    for (int k0 = 0; k0 < K; k0 += 32) {
        // ---- stage A (128 x 32) ----
        {
            const int grow = bm + srow;
            if (A_FP32) {
                uint4 w0, w1;
                if (grow < M) {
                    const float* A = (const float*)Av;
                    const float4* p = (const float4*)&A[(long)grow * K + k0 + skh];
                    float4 f;
                    f = p[0]; w0.x = f2bf_pk(f.x, f.y); w0.y = f2bf_pk(f.z, f.w);
                    f = p[1]; w0.z = f2bf_pk(f.x, f.y); w0.w = f2bf_pk(f.z, f.w);
                    f = p[2]; w1.x = f2bf_pk(f.x, f.y); w1.y = f2bf_pk(f.z, f.w);
                    f = p[3]; w1.z = f2bf_pk(f.x, f.y); w1.w = f2bf_pk(f.z, f.w);
                } else {
                    w0 = make_uint4(0, 0, 0, 0);
                    w1 = make_uint4(0, 0, 0, 0);
                }
                *(uint4*)&As[srow * 40 + skh]     = w0;
                *(uint4*)&As[srow * 40 + skh + 8] = w1;
            } else {
                unsigned short tmp[16];
                const unsigned short* A = (const unsigned short*)Av;
                if (grow < M) {
                    const ushort8* p = (const ushort8*)&A[(long)grow * K + k0 + skh];
                    ushort8 u0 = p[0], u1 = p[1];
#pragma unroll
                    for (int v = 0; v < 8; v++) { tmp[v] = u0[v]; tmp[8 + v] = u1[v]; }
                    if (RELU_A) {
#pragma unroll
                        for (int v = 0; v < 16; v++)
                            if (tmp[v] & 0x8000u) tmp[v] = 0;
                    }
                } else {
#pragma unroll
                    for (int v = 0; v < 16; v++) tmp[v] = 0;
                }
                ushort8* dst = (ushort8*)&As[srow * 40 + skh];
                ushort8 w0, w1;
#pragma unroll
                for (int v = 0; v < 8; v++) { w0[v] = tmp[v]; w1[v] = tmp[8 + v]; }
                dst[0] = w0;
                dst[1] = w1;
            }
        }
        // ---- stage B (BN x 32) ----
        if (BN == 128) {
            const int gn = bn + srow;
            const ushort8* p = (const ushort8*)&BT[(long)gn * K + k0 + skh];
            ushort8* dst = (ushort8*)&Bs[srow * 40 + skh];
            dst[0] = p[0];
            dst[1] = p[1];
        } else {
            const int gn = bn + tid;   // 256 rows, one per thread
            const ushort8* p = (const ushort8*)&BT[(long)gn * K + k0];
            ushort8* dst = (ushort8*)&Bs[tid * 40];
            dst[0] = p[0];
            dst[1] = p[1];
            dst[2] = p[2];
            dst[3] = p[3];
        }
        __syncthreads();

        short8 af[4], bf[NJ];
#pragma unroll
        for (int i = 0; i < 4; i++)
            af[i] = *(const short8*)&As[(wm + i * 16 + mrow) * 40 + q * 8];
#pragma unroll
        for (int j = 0; j < NJ; j++)
            bf[j] = *(const short8*)&Bs[(wn + j * 16 + mrow) * 40 + q * 8];
#pragma unroll
        for (int i = 0; i < 4; i++)
#pragma unroll
            for (int j = 0; j < NJ; j++)
                acc[i][j] = __builtin_amdgcn_mfma_f32_16x16x32_bf16(af[i], bf[j], acc[i][j], 0, 0, 0);
        __syncthreads();
    }

#pragma unroll
    for (int i = 0; i < 4; i++) {
#pragma unroll
        for (int r = 0; r < 4; r++) {
            const int row = bm + wm + i * 16 + q * 4 + r;
            if (row < M) {
#pragma unroll
                for (int j = 0; j < NJ; j++) {
                    const int col = bn + wn + j * 16 + mrow;
                    float v = acc[i][j][r] + bias[col];
                    if (OUT_BF16)
                        ((unsigned short*)Cv)[(long)row * N + col] = f2bf(v);
                    else
                        ((float*)Cv)[(long)row * N + col] = v;
                }
            }
        }
    }
}

// ---------------- launch ----------------

extern "C" void kernel_launch(void* const* d_in, const int* in_sizes, int n_in,
                              void* d_out, int out_size, void* d_ws, size_t ws_size,
                              hipStream_t stream) {
    const float* x    = (const float*)d_in[0];
    const int*   erow = (const int*)d_in[1];
    const int*   ecol = (const int*)d_in[2];
    const float* eval = (const float*)d_in[3];
    const float* W0   = (const float*)d_in[4];
    const float* b0   = (const float*)d_in[5];
    const float* W1   = (const float*)d_in[6];
    const float* b1   = (const float*)d_in[7];
    float* out = (float*)d_out;

    char* ws = (char*)d_ws;
    size_t off = 0;
    auto alloc = [&](size_t bytes) {
        void* p = ws + off;
        off += (bytes + 255) & ~(size_t)255;
        return p;
    };
    int*            gcnt     = (int*)alloc(NBINS * sizeof(int));
    uint2*          binned   = (uint2*)alloc((size_t)NBINS * BINCAP * sizeof(uint2));
    unsigned short* W0T      = (unsigned short*)alloc((size_t)IN_DIM * HD_DIM * sizeof(unsigned short));
    unsigned short* W1T      = (unsigned short*)alloc((size_t)HD_DIM * OUT_DIM * sizeof(unsigned short));
    unsigned short* Ha       = (unsigned short*)alloc((size_t)N_NODES * HD_DIM * sizeof(unsigned short));
    unsigned short* Hb       = (unsigned short*)alloc((size_t)N_NODES * HD_DIM * sizeof(unsigned short));

    const int nblk = (N_EDGES + EPB - 1) / EPB;  // 782

    // CSR level 1 (ws re-poisoned each launch -> zero the per-bin fill counters)
    hipMemsetAsync(gcnt, 0, NBINS * sizeof(int), stream);
    bin_scatter<<<nblk, 256, 0, stream>>>(erow, ecol, eval, gcnt, binned, N_EDGES);

    // fused weight transpose + convert
    transpose_w<<<(IN_DIM * HD_DIM + HD_DIM * OUT_DIM + 255) / 256, 256, 0, stream>>>(
        W0, W0T, W1, W1T);

    // H0 = bf16(x @ W0 + b0)  -- BN=256: single block-column, A read once
    gemm_mfma<true, false, true, 256><<<dim3((N_NODES + 127) / 128, HD_DIM / 256), 256, 0, stream>>>(
        x, W0T, b0, Ha, N_NODES, HD_DIM, IN_DIM);

    // H1 = A @ H0 ; H2 = A @ H1  (both passes: fused sort + segment-major gather)
    spmm_seg<<<NBINS, 256, 0, stream>>>(gcnt, binned, Ha, Hb);
    spmm_seg<<<NBINS, 256, 0, stream>>>(gcnt, binned, Hb, Ha);

    // out = relu(H2) @ W1 + b1  (fp32 out)
    gemm_mfma<false, true, false, 128><<<dim3((N_NODES + 127) / 128, OUT_DIM / 128), 256, 0, stream>>>(
        Ha, W1T, b1, out, N_NODES, OUT_DIM, HD_DIM);
}

// Round 8
// 872.006 us; speedup vs baseline: 1.1442x; 1.1442x over previous
//
#include <hip/hip_runtime.h>

#define N_NODES 100000
#define N_EDGES 3200000
#define IN_DIM  512
#define HD_DIM  256
#define OUT_DIM 128

#define NBINS  391         // bins of 256 rows: bin = row >> 8
#define BINCAP 9216        // fixed slots per bin (mean 8184, sigma ~90 -> 11 sigma)
#define SORT_IT 18         // BINCAP / 512
#define EPT    16          // edges per thread in scatter pass
#define EPB    (256 * EPT) // edges per block = 4096

typedef short   short8  __attribute__((ext_vector_type(8)));
typedef unsigned short ushort8 __attribute__((ext_vector_type(8)));
typedef float   floatx4 __attribute__((ext_vector_type(4)));

__device__ __forceinline__ unsigned short f2bf(float f) {
    unsigned int u = __float_as_uint(f);
    u += 0x7fffu + ((u >> 16) & 1u);   // round-to-nearest-even
    return (unsigned short)(u >> 16);
}

// HW packed fp32->bf16 (RNE), 2 elements per instruction
__device__ __forceinline__ unsigned f2bf_pk(float lo, float hi) {
    unsigned r;
    asm("v_cvt_pk_bf16_f32 %0, %1, %2" : "=v"(r) : "v"(lo), "v"(hi));
    return r;
}

// ---------------- CSR build level 1: staged scatter into 256-row bins (R3-proven) ----------------
// binned layout: bin b owns slots [b*BINCAP, b*BINCAP + cnt[b]); gaps never read.
// packed entry: x = (row_local8 << 20) | col, y = bits(val)

__global__ __launch_bounds__(256) void bin_scatter(const int* __restrict__ erow,
                                                   const int* __restrict__ ecol,
                                                   const float* __restrict__ eval,
                                                   int* __restrict__ gcnt,
                                                   uint2* __restrict__ binned, int E) {
    __shared__ int hist[NBINS];
    __shared__ int sd[512];
    __shared__ int lbase[NBINS];
    __shared__ int gbase[NBINS];
    __shared__ int cur[NBINS];
    __shared__ unsigned short sbin[EPB];   // bin id per staged slot
    __shared__ uint2 sedge[EPB];           // staged edges, grouped by bin

    const int t = threadIdx.x;
    for (int i = t; i < NBINS; i += 256) hist[i] = 0;
    __syncthreads();

    long base = (long)blockIdx.x * EPB + t * EPT;
    int rows[EPT];
    const bool valid = base < E;   // chunks all-in or all-out (E % 16 == 0)
    if (valid) {
        const int4* p = (const int4*)(erow + base);
#pragma unroll
        for (int v = 0; v < 4; v++) {
            int4 r = p[v];
            rows[4 * v + 0] = r.x; rows[4 * v + 1] = r.y;
            rows[4 * v + 2] = r.z; rows[4 * v + 3] = r.w;
        }
#pragma unroll
        for (int u = 0; u < EPT; u++) atomicAdd(&hist[rows[u] >> 8], 1);
    }
    __syncthreads();

    // inclusive scan of hist[0..NBINS) over a 512-wide workspace, 2 slots/thread
    sd[t]       = (t < NBINS) ? hist[t] : 0;
    sd[t + 256] = (t + 256 < NBINS) ? hist[t + 256] : 0;
    __syncthreads();
    for (int off = 1; off < 512; off <<= 1) {
        int a0 = (t >= off) ? sd[t - off] : 0;
        int a1 = (t + 256 >= off) ? sd[t + 256 - off] : 0;
        __syncthreads();
        sd[t] += a0;
        sd[t + 256] += a1;
        __syncthreads();
    }

    // local bases + global run reservation per bin
    for (int i = t; i < NBINS; i += 256) {
        int h  = hist[i];
        int lb = sd[i] - h;
        lbase[i] = lb;
        cur[i]   = lb;
        gbase[i] = h ? (i * BINCAP + atomicAdd(&gcnt[i], h)) : 0;
    }
    __syncthreads();

    // stage edges into LDS grouped by bin
    if (valid) {
        const int4*   pc = (const int4*)(ecol + base);
        const float4* pv = (const float4*)(eval + base);
#pragma unroll
        for (int v = 0; v < 4; v++) {
            int4 c4 = pc[v];
            float4 v4 = pv[v];
            int   cs[4] = {c4.x, c4.y, c4.z, c4.w};
            float vs[4] = {v4.x, v4.y, v4.z, v4.w};
#pragma unroll
            for (int u = 0; u < 4; u++) {
                int r = rows[4 * v + u];
                int bin = r >> 8;
                int lpos = atomicAdd(&cur[bin], 1);
                sedge[lpos] = make_uint2(((unsigned)(r & 255) << 20) | (unsigned)cs[u],
                                         __float_as_uint(vs[u]));
                sbin[lpos] = (unsigned short)bin;
            }
        }
    }
    __syncthreads();

    // coalesced flush: consecutive slots are mostly the same bin -> contiguous runs
    const int ns = sd[NBINS - 1];
    for (int i = t; i < ns; i += 256) {
        int bin = sbin[i];
        int gpos = gbase[bin] + (i - lbase[bin]);
        if (gpos < (bin + 1) * BINCAP)   // safety clamp (11-sigma margin, fixed dataset)
            binned[gpos] = sedge[i];
    }
}

// ---------------- fused level-2 sort + SPMM pass 1 ----------------
// One 512-thread block per 256-row bin (391 blocks, all co-resident at 2/CU):
// sort the bin's edges by row in LDS, emit rowptr + row-sorted csr for pass 2,
// then gather/accumulate directly from the LDS-resident sorted edges using the
// proven 8-deep row loop (edge reads become LDS broadcasts).

__global__ __launch_bounds__(512) void spmm_fuse1(const int* __restrict__ gcnt,
                                                  const uint2* __restrict__ binned,
                                                  int* __restrict__ rowptr,
                                                  int* __restrict__ binend,
                                                  uint2* __restrict__ csr,
                                                  const unsigned short* __restrict__ Hin,
                                                  unsigned short* __restrict__ Hout) {
    __shared__ uint2 ssort[BINCAP];   // 72 KB
    __shared__ int hist[256];
    __shared__ int sd[256];
    __shared__ int cur[256];
    const int t = threadIdx.x;
    const int b = blockIdx.x;
    int n = gcnt[b];
    if (n > BINCAP) n = BINCAP;
    const int s = b * BINCAP;

    if (t < 256) hist[t] = 0;
    __syncthreads();

    // load bin edges into registers (static indices) + row histogram
    uint2 ereg[SORT_IT];
#pragma unroll
    for (int it = 0; it < SORT_IT; it++) {
        int i = it * 512 + t;
        if (i < n) {
            ereg[it] = binned[s + i];
            atomicAdd(&hist[ereg[it].x >> 20], 1);
        }
    }
    __syncthreads();

    // inclusive scan over 256 row-counts (t<256 active, full-block barriers)
    int v = 0;
    if (t < 256) { v = hist[t]; sd[t] = v; }
    __syncthreads();
    for (int off = 1; off < 256; off <<= 1) {
        int add = 0;
        if (t < 256 && t >= off) add = sd[t - off];
        __syncthreads();
        if (t < 256) sd[t] += add;
        __syncthreads();
    }
    if (t < 256) {
        int ex = sd[t] - v;
        cur[t] = ex;
        int r = (b << 8) + t;
        if (r <= N_NODES) rowptr[r] = s + ex;   // r==N_NODES lands in bin 390 (t=160)
    }
    if (t == 0) binend[b] = s + n;
    __syncthreads();

    // scatter into row-sorted LDS array
#pragma unroll
    for (int it = 0; it < SORT_IT; it++) {
        int i = it * 512 + t;
        if (i < n) {
            int rl = ereg[it].x >> 20;
            int p = atomicAdd(&cur[rl], 1);
            ssort[p] = make_uint2(ereg[it].x & 0xFFFFFu, ereg[it].y);
        }
    }
    __syncthreads();

    // coalesced flush of the sorted run for pass 2
    for (int i = t; i < n; i += 512) csr[s + i] = ssort[i];

    // gather phase: 8 waves x 32 rows, proven 8-deep batches, edges via LDS broadcast
    const int wave = t >> 6;
    const int lane = t & 63;
    const uint2* __restrict__ Hv = (const uint2*)Hin;   // H row = 64 uint2
    for (int q = 0; q < 32; q++) {
        const int rl = wave * 32 + q;
        const int r = (b << 8) + rl;
        if (r >= N_NODES) break;                 // wave-uniform (tail bin only)
        const int ke = sd[rl];
        const int ks = ke - hist[rl];
        float a0 = 0.f, a1 = 0.f, a2 = 0.f, a3 = 0.f;
        for (int j0 = ks; j0 < ke; j0 += 8) {
            int m = ke - j0;
            if (m > 8) m = 8;
            uint2 h[8];
            float vv[8];
#pragma unroll
            for (int u = 0; u < 8; u++) {
                if (u < m) {                      // wave-uniform predicate
                    uint2 e = ssort[j0 + u];      // LDS broadcast read
                    vv[u] = __uint_as_float(e.y);
                    h[u]  = Hv[((unsigned)e.x << 6) + lane];
                } else { vv[u] = 0.f; h[u] = make_uint2(0u, 0u); }
            }
#pragma unroll
            for (int u = 0; u < 8; u++) {
                float vu = vv[u];
                a0 += vu * __uint_as_float(h[u].x << 16);
                a1 += vu * __uint_as_float(h[u].x & 0xffff0000u);
                a2 += vu * __uint_as_float(h[u].y << 16);
                a3 += vu * __uint_as_float(h[u].y & 0xffff0000u);
            }
        }
        unsigned long long o = (unsigned long long)((unsigned)f2bf(a0) | ((unsigned)f2bf(a1) << 16))
                             | ((unsigned long long)((unsigned)f2bf(a2) | ((unsigned)f2bf(a3) << 16)) << 32);
        __builtin_nontemporal_store(o, (unsigned long long*)Hout + (((unsigned)r << 6) + lane));
    }
}

// ---------------- fused weight transpose + fp32->bf16: in[K][N] -> out[N][K] ----------------

__global__ void transpose_w(const float* __restrict__ W0, unsigned short* __restrict__ W0T,
                            const float* __restrict__ W1, unsigned short* __restrict__ W1T) {
    int idx = blockIdx.x * blockDim.x + threadIdx.x;
    if (idx < IN_DIM * HD_DIM) {
        int k = idx / HD_DIM, n = idx - k * HD_DIM;
        W0T[n * IN_DIM + k] = f2bf(W0[idx]);
    } else {
        int j = idx - IN_DIM * HD_DIM;
        if (j < HD_DIM * OUT_DIM) {
            int k = j / OUT_DIM, n = j - k * OUT_DIM;
            W1T[n * HD_DIM + k] = f2bf(W1[j]);
        }
    }
}

// ---------------- MFMA bf16 GEMM: C[M,N] = (relu?)A[M,K] @ BT[N,K]^T + bias ----------------
// BK = 32 (R3-proven structure). BN = 128: 4 waves 64x64 (acc[4][4]).
// BN = 256: 4 waves 64x128 (acc[4][8]) -- single block-column so fp32 A is fetched ONCE.

template <bool A_FP32, bool RELU_A, bool OUT_BF16, int BN>
__global__ __launch_bounds__(256, 2) void gemm_mfma(const void* __restrict__ Av,
                                                    const unsigned short* __restrict__ BT,
                                                    const float* __restrict__ bias,
                                                    void* __restrict__ Cv,
                                                    int M, int N, int K) {
    constexpr int NJ = BN / 32;   // N-fragments per wave: 4 or 8
    __shared__ unsigned short As[128 * 40];
    __shared__ unsigned short Bs[BN * 40];
    const int tid  = threadIdx.x;
    const int lane = tid & 63;
    const int wv   = tid >> 6;
    const int wm   = (wv >> 1) * 64;
    const int wn   = (wv & 1) * (BN / 2);
    const int mrow = lane & 15;
    const int q    = lane >> 4;
    const int bm   = blockIdx.x * 128;
    const int bn   = blockIdx.y * BN;

    floatx4 acc[4][NJ] = {};

    const int srow = tid >> 1;
    const int skh  = (tid & 1) * 16;

    for (int k0 = 0; k0 < K; k0 += 32) {
        // ---- stage A (128 x 32) ----
        {
            const int grow = bm + srow;
            if (A_FP32) {
                uint4 w0, w1;
                if (grow < M) {
                    const float* A = (const float*)Av;
                    const float4* p = (const float4*)&A[(long)grow * K + k0 + skh];
                    float4 f;
                    f = p[0]; w0.x = f2bf_pk(f.x, f.y); w0.y = f2bf_pk(f.z, f.w);
                    f = p[1]; w0.z = f2bf_pk(f.x, f.y); w0.w = f2bf_pk(f.z, f.w);
                    f = p[2]; w1.x = f2bf_pk(f.x, f.y); w1.y = f2bf_pk(f.z, f.w);
                    f = p[3]; w1.z = f2bf_pk(f.x, f.y); w1.w = f2bf_pk(f.z, f.w);
                } else {
                    w0 = make_uint4(0, 0, 0, 0);
                    w1 = make_uint4(0, 0, 0, 0);
                }
                *(uint4*)&As[srow * 40 + skh]     = w0;
                *(uint4*)&As[srow * 40 + skh + 8] = w1;
            } else {
                unsigned short tmp[16];
                const unsigned short* A = (const unsigned short*)Av;
                if (grow < M) {
                    const ushort8* p = (const ushort8*)&A[(long)grow * K + k0 + skh];
                    ushort8 u0 = p[0], u1 = p[1];
#pragma unroll
                    for (int v = 0; v < 8; v++) { tmp[v] = u0[v]; tmp[8 + v] = u1[v]; }
                    if (RELU_A) {
#pragma unroll
                        for (int v = 0; v < 16; v++)
                            if (tmp[v] & 0x8000u) tmp[v] = 0;
                    }
                } else {
#pragma unroll
                    for (int v = 0; v < 16; v++) tmp[v] = 0;
                }
                ushort8* dst = (ushort8*)&As[srow * 40 + skh];
                ushort8 w0, w1;
#pragma unroll
                for (int v = 0; v < 8; v++) { w0[v] = tmp[v]; w1[v] = tmp[8 + v]; }
                dst[0] = w0;
                dst[1] = w1;
            }
        }
        // ---- stage B (BN x 32) ----
        if (BN == 128) {
            const int gn = bn + srow;
            const ushort8* p = (const ushort8*)&BT[(long)gn * K + k0 + skh];
            ushort8* dst = (ushort8*)&Bs[srow * 40 + skh];
            dst[0] = p[0];
            dst[1] = p[1];
        } else {
            const int gn = bn + tid;   // 256 rows, one per thread
            const ushort8* p = (const ushort8*)&BT[(long)gn * K + k0];
            ushort8* dst = (ushort8*)&Bs[tid * 40];
            dst[0] = p[0];
            dst[1] = p[1];
            dst[2] = p[2];
            dst[3] = p[3];
        }
        __syncthreads();

        short8 af[4], bf[NJ];
#pragma unroll
        for (int i = 0; i < 4; i++)
            af[i] = *(const short8*)&As[(wm + i * 16 + mrow) * 40 + q * 8];
#pragma unroll
        for (int j = 0; j < NJ; j++)
            bf[j] = *(const short8*)&Bs[(wn + j * 16 + mrow) * 40 + q * 8];
#pragma unroll
        for (int i = 0; i < 4; i++)
#pragma unroll
            for (int j = 0; j < NJ; j++)
                acc[i][j] = __builtin_amdgcn_mfma_f32_16x16x32_bf16(af[i], bf[j], acc[i][j], 0, 0, 0);
        __syncthreads();
    }

#pragma unroll
    for (int i = 0; i < 4; i++) {
#pragma unroll
        for (int r = 0; r < 4; r++) {
            const int row = bm + wm + i * 16 + q * 4 + r;
            if (row < M) {
#pragma unroll
                for (int j = 0; j < NJ; j++) {
                    const int col = bn + wn + j * 16 + mrow;
                    float v = acc[i][j][r] + bias[col];
                    if (OUT_BF16)
                        ((unsigned short*)Cv)[(long)row * N + col] = f2bf(v);
                    else
                        ((float*)Cv)[(long)row * N + col] = v;
                }
            }
        }
    }
}

// ---------------- CSR SPMM pass 2: one wave per row, shfl-broadcast edges (R4-proven) ----------------

__global__ __launch_bounds__(256) void spmm_bf16(const int* __restrict__ rowptr,
                                                 const int* __restrict__ binend,
                                                 const uint2* __restrict__ edges,
                                                 const unsigned short* __restrict__ Hin,
                                                 unsigned short* __restrict__ Hout) {
    const int wave = threadIdx.x >> 6;
    const int lane = threadIdx.x & 63;
    const int r = blockIdx.x * 4 + wave;
    if (r >= N_NODES) return;
    const int s = rowptr[r];
    const int e = ((r & 255) == 255) ? binend[r >> 8] : rowptr[r + 1];
    const uint2* __restrict__ Hv = (const uint2*)Hin;  // row = 64 uint2
    float a0 = 0.f, a1 = 0.f, a2 = 0.f, a3 = 0.f;

    for (int base = s; base < e; base += 64) {
        int idx = base + lane;
        uint2 ev = make_uint2(0u, 0u);
        if (idx < e) {
            unsigned long long raw =
                __builtin_nontemporal_load((const unsigned long long*)edges + idx);
            ev.x = (unsigned)raw;
            ev.y = (unsigned)(raw >> 32);
        }
        int cnt = e - base;
        if (cnt > 64) cnt = 64;
        for (int j0 = 0; j0 < cnt; j0 += 8) {
            uint2 h[8];
            float v[8];
#pragma unroll
            for (int u = 0; u < 8; u++) {
                int   c = __shfl((int)ev.x, j0 + u);
                v[u]    = __uint_as_float((unsigned)__shfl((int)ev.y, j0 + u));
                h[u]    = Hv[((unsigned)c << 6) + lane];
            }
#pragma unroll
            for (int u = 0; u < 8; u++) {
                a0 += v[u] * __uint_as_float(h[u].x << 16);
                a1 += v[u] * __uint_as_float(h[u].x & 0xffff0000u);
                a2 += v[u] * __uint_as_float(h[u].y << 16);
                a3 += v[u] * __uint_as_float(h[u].y & 0xffff0000u);
            }
        }
    }
    unsigned long long o = (unsigned long long)((unsigned)f2bf(a0) | ((unsigned)f2bf(a1) << 16))
                         | ((unsigned long long)((unsigned)f2bf(a2) | ((unsigned)f2bf(a3) << 16)) << 32);
    __builtin_nontemporal_store(o, (unsigned long long*)Hout + (((unsigned)r << 6) + lane));
}

// ---------------- launch ----------------

extern "C" void kernel_launch(void* const* d_in, const int* in_sizes, int n_in,
                              void* d_out, int out_size, void* d_ws, size_t ws_size,
                              hipStream_t stream) {
    const float* x    = (const float*)d_in[0];
    const int*   erow = (const int*)d_in[1];
    const int*   ecol = (const int*)d_in[2];
    const float* eval = (const float*)d_in[3];
    const float* W0   = (const float*)d_in[4];
    const float* b0   = (const float*)d_in[5];
    const float* W1   = (const float*)d_in[6];
    const float* b1   = (const float*)d_in[7];
    float* out = (float*)d_out;

    char* ws = (char*)d_ws;
    size_t off = 0;
    auto alloc = [&](size_t bytes) {
        void* p = ws + off;
        off += (bytes + 255) & ~(size_t)255;
        return p;
    };
    int*            rowptr   = (int*)alloc((N_NODES + 1) * sizeof(int));
    int*            gcnt     = (int*)alloc(NBINS * sizeof(int));
    int*            binend   = (int*)alloc(NBINS * sizeof(int));
    uint2*          binned   = (uint2*)alloc((size_t)NBINS * BINCAP * sizeof(uint2));
    uint2*          csr      = (uint2*)alloc((size_t)NBINS * BINCAP * sizeof(uint2));
    unsigned short* W0T      = (unsigned short*)alloc((size_t)IN_DIM * HD_DIM * sizeof(unsigned short));
    unsigned short* W1T      = (unsigned short*)alloc((size_t)HD_DIM * OUT_DIM * sizeof(unsigned short));
    unsigned short* Ha       = (unsigned short*)alloc((size_t)N_NODES * HD_DIM * sizeof(unsigned short));
    unsigned short* Hb       = (unsigned short*)alloc((size_t)N_NODES * HD_DIM * sizeof(unsigned short));

    const int nblk = (N_EDGES + EPB - 1) / EPB;  // 782

    // CSR level 1 (ws re-poisoned each launch -> zero the per-bin fill counters)
    hipMemsetAsync(gcnt, 0, NBINS * sizeof(int), stream);
    bin_scatter<<<nblk, 256, 0, stream>>>(erow, ecol, eval, gcnt, binned, N_EDGES);

    // fused weight transpose + convert
    transpose_w<<<(IN_DIM * HD_DIM + HD_DIM * OUT_DIM + 255) / 256, 256, 0, stream>>>(
        W0, W0T, W1, W1T);

    // H0 = bf16(x @ W0 + b0)  -- BN=256: single block-column, A read once
    gemm_mfma<true, false, true, 256><<<dim3((N_NODES + 127) / 128, HD_DIM / 256), 256, 0, stream>>>(
        x, W0T, b0, Ha, N_NODES, HD_DIM, IN_DIM);

    // pass 1: fused level-2 sort + H1 = A @ H0 (also emits rowptr/binend/csr for pass 2)
    spmm_fuse1<<<NBINS, 512, 0, stream>>>(gcnt, binned, rowptr, binend, csr, Ha, Hb);

    // pass 2: H2 = A @ H1
    spmm_bf16<<<(N_NODES + 3) / 4, 256, 0, stream>>>(rowptr, binend, csr, Hb, Ha);

    // out = relu(H2) @ W1 + b1  (fp32 out)
    gemm_mfma<false, true, false, 128><<<dim3((N_NODES + 127) / 128, OUT_DIM / 128), 256, 0, stream>>>(
        Ha, W1T, b1, out, N_NODES, OUT_DIM, HD_DIM);
}

// Round 10
// 863.462 us; speedup vs baseline: 1.1555x; 1.0099x over previous
//
#include <hip/hip_runtime.h>

#define N_NODES 100000
#define N_EDGES 3200000
#define IN_DIM  512
#define HD_DIM  256
#define OUT_DIM 128

#define NBINS  391         // bins of 256 rows: bin = row >> 8
#define BINCAP 9216        // fixed slots per bin (mean 8184, sigma ~90 -> 11 sigma)
#define SORT_IT 9          // BINCAP / 1024
#define EPT    16          // edges per thread in scatter pass
#define EPB    (256 * EPT) // edges per block = 4096

typedef short   short8  __attribute__((ext_vector_type(8)));
typedef unsigned short ushort8 __attribute__((ext_vector_type(8)));
typedef float   floatx4 __attribute__((ext_vector_type(4)));

__device__ __forceinline__ unsigned short f2bf(float f) {
    unsigned int u = __float_as_uint(f);
    u += 0x7fffu + ((u >> 16) & 1u);   // round-to-nearest-even
    return (unsigned short)(u >> 16);
}

// HW packed fp32->bf16 (RNE), 2 elements per instruction
__device__ __forceinline__ unsigned f2bf_pk(float lo, float hi) {
    unsigned r;
    asm("v_cvt_pk_bf16_f32 %0, %1, %2" : "=v"(r) : "v"(lo), "v"(hi));
    return r;
}

// ---------------- CSR build level 1: staged scatter into 256-row bins (R3-proven) ----------------
// binned layout: bin b owns slots [b*BINCAP, b*BINCAP + cnt[b]); gaps never read.
// packed entry: x = (row_local8 << 20) | col, y = bits(val)

__global__ __launch_bounds__(256) void bin_scatter(const int* __restrict__ erow,
                                                   const int* __restrict__ ecol,
                                                   const float* __restrict__ eval,
                                                   int* __restrict__ gcnt,
                                                   uint2* __restrict__ binned, int E) {
    __shared__ int hist[NBINS];
    __shared__ int sd[512];
    __shared__ int lbase[NBINS];
    __shared__ int gbase[NBINS];
    __shared__ int cur[NBINS];
    __shared__ unsigned short sbin[EPB];   // bin id per staged slot
    __shared__ uint2 sedge[EPB];           // staged edges, grouped by bin

    const int t = threadIdx.x;
    for (int i = t; i < NBINS; i += 256) hist[i] = 0;
    __syncthreads();

    long base = (long)blockIdx.x * EPB + t * EPT;
    int rows[EPT];
    const bool valid = base < E;   // chunks all-in or all-out (E % 16 == 0)
    if (valid) {
        const int4* p = (const int4*)(erow + base);
#pragma unroll
        for (int v = 0; v < 4; v++) {
            int4 r = p[v];
            rows[4 * v + 0] = r.x; rows[4 * v + 1] = r.y;
            rows[4 * v + 2] = r.z; rows[4 * v + 3] = r.w;
        }
#pragma unroll
        for (int u = 0; u < EPT; u++) atomicAdd(&hist[rows[u] >> 8], 1);
    }
    __syncthreads();

    // inclusive scan of hist[0..NBINS) over a 512-wide workspace, 2 slots/thread
    sd[t]       = (t < NBINS) ? hist[t] : 0;
    sd[t + 256] = (t + 256 < NBINS) ? hist[t + 256] : 0;
    __syncthreads();
    for (int off = 1; off < 512; off <<= 1) {
        int a0 = (t >= off) ? sd[t - off] : 0;
        int a1 = (t + 256 >= off) ? sd[t + 256 - off] : 0;
        __syncthreads();
        sd[t] += a0;
        sd[t + 256] += a1;
        __syncthreads();
    }

    // local bases + global run reservation per bin
    for (int i = t; i < NBINS; i += 256) {
        int h  = hist[i];
        int lb = sd[i] - h;
        lbase[i] = lb;
        cur[i]   = lb;
        gbase[i] = h ? (i * BINCAP + atomicAdd(&gcnt[i], h)) : 0;
    }
    __syncthreads();

    // stage edges into LDS grouped by bin
    if (valid) {
        const int4*   pc = (const int4*)(ecol + base);
        const float4* pv = (const float4*)(eval + base);
#pragma unroll
        for (int v = 0; v < 4; v++) {
            int4 c4 = pc[v];
            float4 v4 = pv[v];
            int   cs[4] = {c4.x, c4.y, c4.z, c4.w};
            float vs[4] = {v4.x, v4.y, v4.z, v4.w};
#pragma unroll
            for (int u = 0; u < 4; u++) {
                int r = rows[4 * v + u];
                int bin = r >> 8;
                int lpos = atomicAdd(&cur[bin], 1);
                sedge[lpos] = make_uint2(((unsigned)(r & 255) << 20) | (unsigned)cs[u],
                                         __float_as_uint(vs[u]));
                sbin[lpos] = (unsigned short)bin;
            }
        }
    }
    __syncthreads();

    // coalesced flush: consecutive slots are mostly the same bin -> contiguous runs
    const int ns = sd[NBINS - 1];
    for (int i = t; i < ns; i += 256) {
        int bin = sbin[i];
        int gpos = gbase[bin] + (i - lbase[bin]);
        if (gpos < (bin + 1) * BINCAP)   // safety clamp (11-sigma margin, fixed dataset)
            binned[gpos] = sedge[i];
    }
}

// ---------------- fused level-2 sort + SPMM pass 1 (1024 threads: 2 blocks/CU = 100% occ) ----------------
// One 1024-thread block per 256-row bin: sort the bin's edges by row in LDS, emit
// rowptr + row-sorted csr for pass 2, then gather/accumulate directly from the
// LDS-resident sorted edges. 16 waves x 16 rows each.

__global__ __launch_bounds__(1024) void spmm_fuse1(const int* __restrict__ gcnt,
                                                   const uint2* __restrict__ binned,
                                                   int* __restrict__ rowptr,
                                                   int* __restrict__ binend,
                                                   uint2* __restrict__ csr,
                                                   const unsigned short* __restrict__ Hin,
                                                   unsigned short* __restrict__ Hout) {
    __shared__ uint2 ssort[BINCAP];   // 72 KB
    __shared__ int hist[256];
    __shared__ int sd[256];
    __shared__ int cur[256];
    const int t = threadIdx.x;
    const int b = blockIdx.x;
    int n = gcnt[b];
    if (n > BINCAP) n = BINCAP;
    const int s = b * BINCAP;

    if (t < 256) hist[t] = 0;
    __syncthreads();

    // load bin edges into registers (static indices) + row histogram
    uint2 ereg[SORT_IT];
#pragma unroll
    for (int it = 0; it < SORT_IT; it++) {
        int i = it * 1024 + t;
        if (i < n) {
            ereg[it] = binned[s + i];
            atomicAdd(&hist[ereg[it].x >> 20], 1);
        }
    }
    __syncthreads();

    // inclusive scan over 256 row-counts (t<256 active, full-block barriers)
    int v = 0;
    if (t < 256) { v = hist[t]; sd[t] = v; }
    __syncthreads();
    for (int off = 1; off < 256; off <<= 1) {
        int add = 0;
        if (t < 256 && t >= off) add = sd[t - off];
        __syncthreads();
        if (t < 256) sd[t] += add;
        __syncthreads();
    }
    if (t < 256) {
        int ex = sd[t] - v;
        cur[t] = ex;
        int r = (b << 8) + t;
        if (r <= N_NODES) rowptr[r] = s + ex;   // r==N_NODES lands in bin 390 (t=160)
    }
    if (t == 0) binend[b] = s + n;
    __syncthreads();

    // scatter into row-sorted LDS array
#pragma unroll
    for (int it = 0; it < SORT_IT; it++) {
        int i = it * 1024 + t;
        if (i < n) {
            int rl = ereg[it].x >> 20;
            int p = atomicAdd(&cur[rl], 1);
            ssort[p] = make_uint2(ereg[it].x & 0xFFFFFu, ereg[it].y);
        }
    }
    __syncthreads();

    // coalesced flush of the sorted run for pass 2
    for (int i = t; i < n; i += 1024) csr[s + i] = ssort[i];

    // gather phase: 16 waves x 16 rows, proven 8-deep batches, edges via LDS broadcast
    const int wave = t >> 6;
    const int lane = t & 63;
    const uint2* __restrict__ Hv = (const uint2*)Hin;   // H row = 64 uint2
    for (int q = 0; q < 16; q++) {
        const int rl = wave * 16 + q;
        const int r = (b << 8) + rl;
        if (r >= N_NODES) break;                 // wave-uniform (tail bin only)
        const int ke = sd[rl];
        const int ks = ke - hist[rl];
        float a0 = 0.f, a1 = 0.f, a2 = 0.f, a3 = 0.f;
        for (int j0 = ks; j0 < ke; j0 += 8) {
            int m = ke - j0;
            if (m > 8) m = 8;
            uint2 h[8];
            float vv[8];
#pragma unroll
            for (int u = 0; u < 8; u++) {
                if (u < m) {                      // wave-uniform predicate
                    uint2 e = ssort[j0 + u];      // LDS broadcast read
                    vv[u] = __uint_as_float(e.y);
                    h[u]  = Hv[((unsigned)e.x << 6) + lane];
                } else { vv[u] = 0.f; h[u] = make_uint2(0u, 0u); }
            }
#pragma unroll
            for (int u = 0; u < 8; u++) {
                float vu = vv[u];
                a0 += vu * __uint_as_float(h[u].x << 16);
                a1 += vu * __uint_as_float(h[u].x & 0xffff0000u);
                a2 += vu * __uint_as_float(h[u].y << 16);
                a3 += vu * __uint_as_float(h[u].y & 0xffff0000u);
            }
        }
        unsigned long long o = (unsigned long long)((unsigned)f2bf(a0) | ((unsigned)f2bf(a1) << 16))
                             | ((unsigned long long)((unsigned)f2bf(a2) | ((unsigned)f2bf(a3) << 16)) << 32);
        __builtin_nontemporal_store(o, (unsigned long long*)Hout + (((unsigned)r << 6) + lane));
    }
}

// ---------------- fused weight transpose + fp32->bf16 (+ gcnt zeroing, runs first) ----------------

__global__ void transpose_w(const float* __restrict__ W0, unsigned short* __restrict__ W0T,
                            const float* __restrict__ W1, unsigned short* __restrict__ W1T,
                            int* __restrict__ gcnt) {
    if (blockIdx.x == 0) {
        for (int i = threadIdx.x; i < NBINS; i += 256) gcnt[i] = 0;
    }
    int idx = blockIdx.x * blockDim.x + threadIdx.x;
    if (idx < IN_DIM * HD_DIM) {
        int k = idx / HD_DIM, n = idx - k * HD_DIM;
        W0T[n * IN_DIM + k] = f2bf(W0[idx]);
    } else {
        int j = idx - IN_DIM * HD_DIM;
        if (j < HD_DIM * OUT_DIM) {
            int k = j / OUT_DIM, n = j - k * OUT_DIM;
            W1T[n * HD_DIM + k] = f2bf(W1[j]);
        }
    }
}

// ---------------- MFMA bf16 GEMM: C[M,N] = (relu?)A[M,K] @ BT[N,K]^T + bias ----------------
// BK = 32 (R3-proven structure). BN = 128: 4 waves 64x64 (acc[4][4]).
// BN = 256: 4 waves 64x128 (acc[4][8]) -- single block-column so fp32 A is fetched ONCE.

template <bool A_FP32, bool RELU_A, bool OUT_BF16, int BN>
__global__ __launch_bounds__(256, 2) void gemm_mfma(const void* __restrict__ Av,
                                                    const unsigned short* __restrict__ BT,
                                                    const float* __restrict__ bias,
                                                    void* __restrict__ Cv,
                                                    int M, int N, int K) {
    constexpr int NJ = BN / 32;   // N-fragments per wave: 4 or 8
    __shared__ unsigned short As[128 * 40];
    __shared__ unsigned short Bs[BN * 40];
    const int tid  = threadIdx.x;
    const int lane = tid & 63;
    const int wv   = tid >> 6;
    const int wm   = (wv >> 1) * 64;
    const int wn   = (wv & 1) * (BN / 2);
    const int mrow = lane & 15;
    const int q    = lane >> 4;
    const int bm   = blockIdx.x * 128;
    const int bn   = blockIdx.y * BN;

    floatx4 acc[4][NJ] = {};

    const int srow = tid >> 1;
    const int skh  = (tid & 1) * 16;

    for (int k0 = 0; k0 < K; k0 += 32) {
        // ---- stage A (128 x 32) ----
        {
            const int grow = bm + srow;
            if (A_FP32) {
                uint4 w0, w1;
                if (grow < M) {
                    const float* A = (const float*)Av;
                    const float4* p = (const float4*)&A[(long)grow * K + k0 + skh];
                    float4 f;
                    f = p[0]; w0.x = f2bf_pk(f.x, f.y); w0.y = f2bf_pk(f.z, f.w);
                    f = p[1]; w0.z = f2bf_pk(f.x, f.y); w0.w = f2bf_pk(f.z, f.w);
                    f = p[2]; w1.x = f2bf_pk(f.x, f.y); w1.y = f2bf_pk(f.z, f.w);
                    f = p[3]; w1.z = f2bf_pk(f.x, f.y); w1.w = f2bf_pk(f.z, f.w);
                } else {
                    w0 = make_uint4(0, 0, 0, 0);
                    w1 = make_uint4(0, 0, 0, 0);
                }
                *(uint4*)&As[srow * 40 + skh]     = w0;
                *(uint4*)&As[srow * 40 + skh + 8] = w1;
            } else {
                unsigned short tmp[16];
                const unsigned short* A = (const unsigned short*)Av;
                if (grow < M) {
                    const ushort8* p = (const ushort8*)&A[(long)grow * K + k0 + skh];
                    ushort8 u0 = p[0], u1 = p[1];
#pragma unroll
                    for (int v = 0; v < 8; v++) { tmp[v] = u0[v]; tmp[8 + v] = u1[v]; }
                    if (RELU_A) {
#pragma unroll
                        for (int v = 0; v < 16; v++)
                            if (tmp[v] & 0x8000u) tmp[v] = 0;
                    }
                } else {
#pragma unroll
                    for (int v = 0; v < 16; v++) tmp[v] = 0;
                }
                ushort8* dst = (ushort8*)&As[srow * 40 + skh];
                ushort8 w0, w1;
#pragma unroll
                for (int v = 0; v < 8; v++) { w0[v] = tmp[v]; w1[v] = tmp[8 + v]; }
                dst[0] = w0;
                dst[1] = w1;
            }
        }
        // ---- stage B (BN x 32) ----
        if (BN == 128) {
            const int gn = bn + srow;
            const ushort8* p = (const ushort8*)&BT[(long)gn * K + k0 + skh];
            ushort8* dst = (ushort8*)&Bs[srow * 40 + skh];
            dst[0] = p[0];
            dst[1] = p[1];
        } else {
            const int gn = bn + tid;   // 256 rows, one per thread
            const ushort8* p = (const ushort8*)&BT[(long)gn * K + k0];
            ushort8* dst = (ushort8*)&Bs[tid * 40];
            dst[0] = p[0];
            dst[1] = p[1];
            dst[2] = p[2];
            dst[3] = p[3];
        }
        __syncthreads();

        short8 af[4], bf[NJ];
#pragma unroll
        for (int i = 0; i < 4; i++)
            af[i] = *(const short8*)&As[(wm + i * 16 + mrow) * 40 + q * 8];
#pragma unroll
        for (int j = 0; j < NJ; j++)
            bf[j] = *(const short8*)&Bs[(wn + j * 16 + mrow) * 40 + q * 8];
#pragma unroll
        for (int i = 0; i < 4; i++)
#pragma unroll
            for (int j = 0; j < NJ; j++)
                acc[i][j] = __builtin_amdgcn_mfma_f32_16x16x32_bf16(af[i], bf[j], acc[i][j], 0, 0, 0);
        __syncthreads();
    }

#pragma unroll
    for (int i = 0; i < 4; i++) {
#pragma unroll
        for (int r = 0; r < 4; r++) {
            const int row = bm + wm + i * 16 + q * 4 + r;
            if (row < M) {
#pragma unroll
                for (int j = 0; j < NJ; j++) {
                    const int col = bn + wn + j * 16 + mrow;
                    float v = acc[i][j][r] + bias[col];
                    if (OUT_BF16)
                        ((unsigned short*)Cv)[(long)row * N + col] = f2bf(v);
                    else
                        ((float*)Cv)[(long)row * N + col] = v;
                }
            }
        }
    }
}

// ---------------- CSR SPMM pass 2: one wave per row, shfl-broadcast edges (R4-proven) ----------------

__global__ __launch_bounds__(256) void spmm_bf16(const int* __restrict__ rowptr,
                                                 const int* __restrict__ binend,
                                                 const uint2* __restrict__ edges,
                                                 const unsigned short* __restrict__ Hin,
                                                 unsigned short* __restrict__ Hout) {
    const int wave = threadIdx.x >> 6;
    const int lane = threadIdx.x & 63;
    const int r = blockIdx.x * 4 + wave;
    if (r >= N_NODES) return;
    const int s = rowptr[r];
    const int e = ((r & 255) == 255) ? binend[r >> 8] : rowptr[r + 1];
    const uint2* __restrict__ Hv = (const uint2*)Hin;  // row = 64 uint2
    float a0 = 0.f, a1 = 0.f, a2 = 0.f, a3 = 0.f;

    for (int base = s; base < e; base += 64) {
        int idx = base + lane;
        uint2 ev = make_uint2(0u, 0u);
        if (idx < e) {
            unsigned long long raw =
                __builtin_nontemporal_load((const unsigned long long*)edges + idx);
            ev.x = (unsigned)raw;
            ev.y = (unsigned)(raw >> 32);
        }
        int cnt = e - base;
        if (cnt > 64) cnt = 64;
        for (int j0 = 0; j0 < cnt; j0 += 8) {
            uint2 h[8];
            float v[8];
#pragma unroll
            for (int u = 0; u < 8; u++) {
                int   c = __shfl((int)ev.x, j0 + u);
                v[u]    = __uint_as_float((unsigned)__shfl((int)ev.y, j0 + u));
                h[u]    = Hv[((unsigned)c << 6) + lane];
            }
#pragma unroll
            for (int u = 0; u < 8; u++) {
                a0 += v[u] * __uint_as_float(h[u].x << 16);
                a1 += v[u] * __uint_as_float(h[u].x & 0xffff0000u);
                a2 += v[u] * __uint_as_float(h[u].y << 16);
                a3 += v[u] * __uint_as_float(h[u].y & 0xffff0000u);
            }
        }
    }
    unsigned long long o = (unsigned long long)((unsigned)f2bf(a0) | ((unsigned)f2bf(a1) << 16))
                         | ((unsigned long long)((unsigned)f2bf(a2) | ((unsigned)f2bf(a3) << 16)) << 32);
    __builtin_nontemporal_store(o, (unsigned long long*)Hout + (((unsigned)r << 6) + lane));
}

// ---------------- launch ----------------

extern "C" void kernel_launch(void* const* d_in, const int* in_sizes, int n_in,
                              void* d_out, int out_size, void* d_ws, size_t ws_size,
                              hipStream_t stream) {
    const float* x    = (const float*)d_in[0];
    const int*   erow = (const int*)d_in[1];
    const int*   ecol = (const int*)d_in[2];
    const float* eval = (const float*)d_in[3];
    const float* W0   = (const float*)d_in[4];
    const float* b0   = (const float*)d_in[5];
    const float* W1   = (const float*)d_in[6];
    const float* b1   = (const float*)d_in[7];
    float* out = (float*)d_out;

    char* ws = (char*)d_ws;
    size_t off = 0;
    auto alloc = [&](size_t bytes) {
        void* p = ws + off;
        off += (bytes + 255) & ~(size_t)255;
        return p;
    };
    int*            rowptr   = (int*)alloc((N_NODES + 1) * sizeof(int));
    int*            gcnt     = (int*)alloc(NBINS * sizeof(int));
    int*            binend   = (int*)alloc(NBINS * sizeof(int));
    uint2*          binned   = (uint2*)alloc((size_t)NBINS * BINCAP * sizeof(uint2));
    uint2*          csr      = (uint2*)alloc((size_t)NBINS * BINCAP * sizeof(uint2));
    unsigned short* W0T      = (unsigned short*)alloc((size_t)IN_DIM * HD_DIM * sizeof(unsigned short));
    unsigned short* W1T      = (unsigned short*)alloc((size_t)HD_DIM * OUT_DIM * sizeof(unsigned short));
    unsigned short* Ha       = (unsigned short*)alloc((size_t)N_NODES * HD_DIM * sizeof(unsigned short));
    unsigned short* Hb       = (unsigned short*)alloc((size_t)N_NODES * HD_DIM * sizeof(unsigned short));

    const int nblk = (N_EDGES + EPB - 1) / EPB;  // 782

    // transpose + convert weights; also zeroes gcnt (ws re-poisoned each launch)
    transpose_w<<<(IN_DIM * HD_DIM + HD_DIM * OUT_DIM + 255) / 256, 256, 0, stream>>>(
        W0, W0T, W1, W1T, gcnt);

    // CSR level 1
    bin_scatter<<<nblk, 256, 0, stream>>>(erow, ecol, eval, gcnt, binned, N_EDGES);

    // H0 = bf16(x @ W0 + b0)  -- BN=256: single block-column, A read once
    gemm_mfma<true, false, true, 256><<<dim3((N_NODES + 127) / 128, HD_DIM / 256), 256, 0, stream>>>(
        x, W0T, b0, Ha, N_NODES, HD_DIM, IN_DIM);

    // pass 1: fused level-2 sort + H1 = A @ H0 (emits rowptr/binend/csr for pass 2)
    spmm_fuse1<<<NBINS, 1024, 0, stream>>>(gcnt, binned, rowptr, binend, csr, Ha, Hb);

    // pass 2: H2 = A @ H1
    spmm_bf16<<<(N_NODES + 3) / 4, 256, 0, stream>>>(rowptr, binend, csr, Hb, Ha);

    // out = relu(H2) @ W1 + b1  (fp32 out)
    gemm_mfma<false, true, false, 128><<<dim3((N_NODES + 127) / 128, OUT_DIM / 128), 256, 0, stream>>>(
        Ha, W1T, b1, out, N_NODES, OUT_DIM, HD_DIM);
}